// Round 4
// baseline (413.935 us; speedup 1.0000x reference)
//
#include <hip/hip_runtime.h>
#include <hip/hip_bf16.h>

#define B_   2
#define N_   2048
#define CIN  256
#define NH   8
#define CH   32

typedef unsigned short u16;
typedef __attribute__((ext_vector_type(4))) float f32x4;
typedef __bf16 bf16x8 __attribute__((ext_vector_type(8)));
typedef u16 u16x4 __attribute__((ext_vector_type(4)));
typedef u16 u16x8 __attribute__((ext_vector_type(8)));

static __device__ __forceinline__ u16 b16(float f) {
    __bf16 h = (__bf16)f;
    union { __bf16 h; u16 u; } c; c.h = h; return c.u;
}
static __device__ __forceinline__ float bf2f(u16 u) {
    union { unsigned u; float f; } c; c.u = ((unsigned)u) << 16; return c.f;
}
static __device__ __forceinline__ float sigmoidf_(float x) {
    return 1.0f / (1.0f + __expf(-x));
}
static __device__ __forceinline__ void gload_lds16(const void* g, void* lds) {
    __builtin_amdgcn_global_load_lds(
        (const __attribute__((address_space(1))) unsigned int*)g,
        (__attribute__((address_space(3))) unsigned int*)lds, 16, 0, 0);
}

// ---------------------------------------------------------------------------
// MEGA-KERNEL with ordered work-queue.
// Items (in queue order): [0,80) weight transpose | [80,1104) proj |
// [1104,1616) attn | [1616,1872) out-proj.
// Deadlock-free at ANY block residency: a block pulls item J only while
// running; the atomic queue counter is monotonic, so every item D < J that J
// depends on has already been pulled by some running block; D's deps point
// further backward (induction, base = stage0 has no deps) so D completes.
// Cross-stage visibility: producers do wg-barrier then agent-scope RELEASE
// fetch_add on a done-counter; consumers spin with agent-scope ACQUIRE loads.
// prep's x->bf16 pass is gone: proj stages A-tiles directly from f32 with
// identical b16() conversion -> bit-identical results.
// ---------------------------------------------------------------------------
#define LDW 136   // padded LDS row (u16): 272B; 272 mod 128 = 16B -> conflict-free b128 reads

typedef union {
    float T[64][65];                                      // stage0 transpose scratch
    struct { u16 At[64][LDW]; u16 Bt[64][LDW]; } g;       // GEMM tiles (34.8 KB)
    struct { float Btl[4][3][16][32]; u16 Plds[4][8][4][16]; } a;  // attn (28 KB)
} SharedU;

// ---- staging helpers (64 rows x 128 k per phase) ----
static __device__ __forceinline__ u16x8 cvt8(float4 a, float4 b) {
    u16x8 o;
    o[0] = b16(a.x); o[1] = b16(a.y); o[2] = b16(a.z); o[3] = b16(a.w);
    o[4] = b16(b.x); o[5] = b16(b.y); o[6] = b16(b.z); o[7] = b16(b.w);
    return o;
}
static __device__ __forceinline__ void stg_b16(const u16* __restrict__ src, u16 (*dst)[LDW], int tid) {
#pragma unroll
    for (int i = 0; i < 4; i++) {
        const int e = tid + 256 * i, row = e >> 4, c = e & 15;
        *(bf16x8*)&dst[row][c * 8] = *(const bf16x8*)(src + (size_t)row * CIN + c * 8);
    }
}
static __device__ __forceinline__ void ld1_b16(const u16* __restrict__ src, bf16x8 r[4], int tid) {
#pragma unroll
    for (int i = 0; i < 4; i++) {
        const int e = tid + 256 * i, row = e >> 4, c = e & 15;
        r[i] = *(const bf16x8*)(src + (size_t)row * CIN + 128 + c * 8);
    }
}
static __device__ __forceinline__ void wr1_b16(const bf16x8 r[4], u16 (*dst)[LDW], int tid) {
#pragma unroll
    for (int i = 0; i < 4; i++) {
        const int e = tid + 256 * i, row = e >> 4, c = e & 15;
        *(bf16x8*)&dst[row][c * 8] = r[i];
    }
}
static __device__ __forceinline__ void stg_f32(const float* __restrict__ src, u16 (*dst)[LDW], int tid) {
#pragma unroll
    for (int i = 0; i < 4; i++) {
        const int e = tid + 256 * i, row = e >> 4, c = e & 15;
        const float* s = src + (size_t)row * CIN + c * 8;
        *(u16x8*)&dst[row][c * 8] = cvt8(*(const float4*)s, *(const float4*)(s + 4));
    }
}
static __device__ __forceinline__ void compute_phase(
    const u16 (*At)[LDW], const u16 (*Bt)[LDW], int w, int lr, int lq, f32x4 acc[4])
{
#pragma unroll
    for (int kk = 0; kk < 128; kk += 32) {
        bf16x8 af = *(const bf16x8*)&At[w * 16 + lr][kk + lq * 8];
#pragma unroll
        for (int nt = 0; nt < 4; nt++) {
            bf16x8 bf = *(const bf16x8*)&Bt[nt * 16 + lr][kk + lq * 8];
            acc[nt] = __builtin_amdgcn_mfma_f32_16x16x32_bf16(af, bf, acc[nt], 0, 0, 0);
        }
    }
}

#define RMAX(x) { x = fmaxf(x, __shfl_xor(x, 1)); x = fmaxf(x, __shfl_xor(x, 2)); \
                  x = fmaxf(x, __shfl_xor(x, 4)); x = fmaxf(x, __shfl_xor(x, 8)); }
#define RSUM(x) { x += __shfl_xor(x, 1); x += __shfl_xor(x, 2); \
                  x += __shfl_xor(x, 4); x += __shfl_xor(x, 8); }

#define NIT0 80
#define NIT1 1024
#define NIT2 512
#define NIT3 256
#define IT1  (NIT0)
#define IT2  (NIT0 + NIT1)
#define IT3  (NIT0 + NIT1 + NIT2)
#define ITOT (NIT0 + NIT1 + NIT2 + NIT3)

static __device__ __forceinline__ void wait_done(unsigned* p, unsigned need) {
    while (__hip_atomic_load(p, __ATOMIC_ACQUIRE, __HIP_MEMORY_SCOPE_AGENT) < need)
        __builtin_amdgcn_s_sleep(8);
}

__global__ __launch_bounds__(256)
void mega_kernel(const float* __restrict__ qx, const float* __restrict__ kvx,
                 const float* __restrict__ bias,
                 const float* __restrict__ Wq, const float* __restrict__ Wk,
                 const float* __restrict__ Wv, const float* __restrict__ Wg,
                 const float* __restrict__ bgv,
                 const float* __restrict__ Wo, const float* __restrict__ bo,
                 u16* __restrict__ WqT, u16* __restrict__ WkT,
                 u16* __restrict__ WvT, u16* __restrict__ WgT, u16* __restrict__ WoT,
                 u16* __restrict__ Qw, u16* __restrict__ Kw,
                 u16* __restrict__ Vt, u16* __restrict__ Gw, u16* __restrict__ Owg,
                 float* __restrict__ out, unsigned* __restrict__ ctr)
{
    const int tid = threadIdx.x;
    const int w = tid >> 6, l = tid & 63, lr = l & 15, lq = l >> 4;
    __shared__ SharedU sh;
    __shared__ int s_item;

    for (;;) {
        __syncthreads();                               // LDS/WAR + s_item guard
        if (tid == 0) s_item = (int)atomicAdd(&ctr[0], 1u);
        __syncthreads();
        const int item = s_item;
        if (item >= ITOT) return;

        int stage;
        if (item < IT1) {
            // ---------------- stage 0: weight transpose+convert ----------------
            stage = 0;
            const int wz = item;
            const int z = wz >> 4, t16 = wz & 15;
            const int k0 = (t16 & 3) * 64, n0 = (t16 >> 2) * 64;
            const float* W = (z == 0) ? Wq : (z == 1) ? Wk : (z == 2) ? Wv : (z == 3) ? Wg : Wo;
            u16* Wt = (z == 0) ? WqT : (z == 1) ? WkT : (z == 2) ? WvT : (z == 3) ? WgT : WoT;
            const float s = (z == 0) ? 0.17677669529663687f : 1.0f;
            const int a = tid >> 4, c4 = (tid & 15) * 4;
#pragma unroll
            for (int i = 0; i < 4; i++) {
                float4 v = *(const float4*)&W[(size_t)(k0 + a + i * 16) * CIN + n0 + c4];
                sh.T[a + i * 16][c4 + 0] = v.x * s; sh.T[a + i * 16][c4 + 1] = v.y * s;
                sh.T[a + i * 16][c4 + 2] = v.z * s; sh.T[a + i * 16][c4 + 3] = v.w * s;
            }
            __syncthreads();
#pragma unroll
            for (int i = 0; i < 4; i++) {
                const int nr = a + i * 16;
                u16x4 o;
                o[0] = b16(sh.T[c4 + 0][nr]); o[1] = b16(sh.T[c4 + 1][nr]);
                o[2] = b16(sh.T[c4 + 2][nr]); o[3] = b16(sh.T[c4 + 3][nr]);
                *(u16x4*)&Wt[(size_t)(n0 + nr) * CIN + k0 + c4] = o;
            }
        } else if (item < IT2) {
            // ---------------- stage 1: projections ----------------
            stage = 1;
            wait_done(&ctr[1], NIT0);
            const int j = item - IT1;
            const int z = j >> 8, y = (j >> 2) & 63, x = j & 3;
            f32x4 acc[4] = {{0,0,0,0},{0,0,0,0},{0,0,0,0},{0,0,0,0}};

            if (z != 2) {
                const float* Af = ((z == 1) ? kvx : qx) + (size_t)(y * 64) * CIN;
                const u16*   Bb = ((z == 0) ? WqT : (z == 1) ? WkT : WgT) + (size_t)(x * 64) * CIN;
                stg_f32(Af, sh.g.At, tid);
                stg_b16(Bb, sh.g.Bt, tid);
                __syncthreads();
                float4 raf[8]; bf16x8 rb[4];
#pragma unroll
                for (int i = 0; i < 4; i++) {
                    const int e = tid + 256 * i, row = e >> 4, c = e & 15;
                    const float* s = Af + (size_t)row * CIN + 128 + c * 8;
                    raf[2 * i] = *(const float4*)s; raf[2 * i + 1] = *(const float4*)(s + 4);
                }
                ld1_b16(Bb, rb, tid);
                compute_phase(sh.g.At, sh.g.Bt, w, lr, lq, acc);
                __syncthreads();
#pragma unroll
                for (int i = 0; i < 4; i++) {
                    const int e = tid + 256 * i, row = e >> 4, c = e & 15;
                    *(u16x8*)&sh.g.At[row][c * 8] = cvt8(raf[2 * i], raf[2 * i + 1]);
                }
                wr1_b16(rb, sh.g.Bt, tid);
                __syncthreads();
                compute_phase(sh.g.At, sh.g.Bt, w, lr, lq, acc);

                const int m0 = y * 64 + w * 16, n0 = x * 64;
                if (z == 3) {
#pragma unroll
                    for (int nt = 0; nt < 4; nt++) {
                        const int col = n0 + nt * 16 + lr;
                        const float bb = bgv[col];
#pragma unroll
                        for (int r = 0; r < 4; r++)
                            Gw[(size_t)(m0 + lq * 4 + r) * CIN + col] = b16(sigmoidf_(acc[nt][r] + bb));
                    }
                } else {
                    u16* D = (z == 0) ? Qw : Kw;
#pragma unroll
                    for (int nt = 0; nt < 4; nt++)
#pragma unroll
                        for (int r = 0; r < 4; r++)
                            D[(size_t)(m0 + lq * 4 + r) * CIN + n0 + nt * 16 + lr] = b16(acc[nt][r]);
                }
            } else {
                const u16*   Ab = WvT + (size_t)(x * 64) * CIN;
                const float* Bf = kvx + (size_t)(y * 64) * CIN;
                stg_b16(Ab, sh.g.At, tid);
                stg_f32(Bf, sh.g.Bt, tid);
                __syncthreads();
                bf16x8 ra[4]; float4 rbf[8];
                ld1_b16(Ab, ra, tid);
#pragma unroll
                for (int i = 0; i < 4; i++) {
                    const int e = tid + 256 * i, row = e >> 4, c = e & 15;
                    const float* s = Bf + (size_t)row * CIN + 128 + c * 8;
                    rbf[2 * i] = *(const float4*)s; rbf[2 * i + 1] = *(const float4*)(s + 4);
                }
                compute_phase(sh.g.At, sh.g.Bt, w, lr, lq, acc);
                __syncthreads();
                wr1_b16(ra, sh.g.At, tid);
#pragma unroll
                for (int i = 0; i < 4; i++) {
                    const int e = tid + 256 * i, row = e >> 4, c = e & 15;
                    *(u16x8*)&sh.g.Bt[row][c * 8] = cvt8(rbf[2 * i], rbf[2 * i + 1]);
                }
                __syncthreads();
                compute_phase(sh.g.At, sh.g.Bt, w, lr, lq, acc);

                const int c0 = x * 64 + w * 16;
                const int n0g = y * 64;
                const int bb_ = n0g >> 11, nl0 = n0g & (N_ - 1);
#pragma unroll
                for (int nt = 0; nt < 4; nt++)
#pragma unroll
                    for (int r = 0; r < 4; r++)
                        Vt[((size_t)bb_ * CIN + c0 + lq * 4 + r) * N_ + nl0 + nt * 16 + lr] = b16(acc[nt][r]);
            }
        } else if (item < IT3) {
            // ---------------- stage 2: flash attention (barrier-free) ----------------
            stage = 2;
            wait_done(&ctr[2], NIT1);
            const int bid = item - IT2;
            const int h = bid & 7, qt = (bid >> 3) & 31, b = bid >> 8;
            const int qb = qt * 64;

            const bf16x8 qf = *(const bf16x8*)(Qw + (size_t)(b * N_ + qb + w * 16 + lr) * CIN + h * CH + lq * 8);
            const u16* Kb = Kw + (size_t)(b * N_ + lr) * CIN + h * CH + lq * 8;
            const u16* Vb = Vt + (size_t)((b * NH + h) * CH + lr) * N_ + lq * 8;
            const float* biasW = bias + ((size_t)(b * NH + h) * N_ + qb + w * 16) * N_;
            const float* gl0 = biasW + (size_t)(l >> 3) * N_ + (l & 7) * 4;
            const float* gl1 = biasW + (size_t)(8 + (l >> 3)) * N_ + (l & 7) * 4;

#define STAGE(TT, BI) { \
    gload_lds16(gl0 + (size_t)(TT) * 32, &sh.a.Btl[w][BI][0][0]); \
    gload_lds16(gl1 + (size_t)(TT) * 32, &sh.a.Btl[w][BI][8][0]); }
#define KVLOAD(K) { kf0 = *(const bf16x8*)(Kb + (size_t)(K) * CIN); \
                    kf1 = *(const bf16x8*)(Kb + (size_t)((K) + 16) * CIN); \
                    vf0 = *(const bf16x8*)(Vb + (K)); \
                    vf1 = *(const bf16x8*)(Vb + 16 * N_ + (K)); }

            f32x4 acc0 = {0.f, 0.f, 0.f, 0.f}, acc1 = {0.f, 0.f, 0.f, 0.f};
            float m0v = 8.f, m1v = 8.f, m2v = 8.f, m3v = 8.f;
            float l0 = 0.f, l1 = 0.f, l2 = 0.f, l3 = 0.f;
            bf16x8 kf0, kf1, vf0, vf1;

            STAGE(0, 0)
            __builtin_amdgcn_sched_barrier(0);
            KVLOAD(0)
            __builtin_amdgcn_sched_barrier(0);
            STAGE(1, 1)
            __builtin_amdgcn_sched_barrier(0);

            int cur = 0, nxt = 2;
            for (int t = 0; t < 64; t++) {
                asm volatile("s_waitcnt vmcnt(2)" ::: "memory");
                const bf16x8 ck0 = kf0, ck1 = kf1, cv0 = vf0, cv1 = vf1;
                KVLOAD(((t + 1) & 63) * 32)
                __builtin_amdgcn_sched_barrier(0);
                STAGE((t + 2) & 63, nxt)
                __builtin_amdgcn_sched_barrier(0);

                const float* bt = &sh.a.Btl[w][cur][lq * 4][0];
                f32x4 c0, c1;
                c0[0] = bt[0 * 32 + lr];      c0[1] = bt[1 * 32 + lr];
                c0[2] = bt[2 * 32 + lr];      c0[3] = bt[3 * 32 + lr];
                c1[0] = bt[0 * 32 + 16 + lr]; c1[1] = bt[1 * 32 + 16 + lr];
                c1[2] = bt[2 * 32 + 16 + lr]; c1[3] = bt[3 * 32 + 16 + lr];

                f32x4 s0 = __builtin_amdgcn_mfma_f32_16x16x32_bf16(qf, ck0, c0, 0, 0, 0);
                f32x4 s1 = __builtin_amdgcn_mfma_f32_16x16x32_bf16(qf, ck1, c1, 0, 0, 0);

                float pm0 = fmaxf(s0[0], s1[0]);
                float pm1 = fmaxf(s0[1], s1[1]);
                float pm2 = fmaxf(s0[2], s1[2]);
                float pm3 = fmaxf(s0[3], s1[3]);
                bool ev = (pm0 > m0v) || (pm1 > m1v) || (pm2 > m2v) || (pm3 > m3v);
                if (__any(ev)) {
                    RMAX(pm0) RMAX(pm1) RMAX(pm2) RMAX(pm3)
                    float t0 = fmaxf(m0v, pm0), t1 = fmaxf(m1v, pm1);
                    float t2 = fmaxf(m2v, pm2), t3 = fmaxf(m3v, pm3);
                    float sc0 = __expf(m0v - t0), sc1 = __expf(m1v - t1);
                    float sc2 = __expf(m2v - t2), sc3 = __expf(m3v - t3);
                    m0v = t0; m1v = t1; m2v = t2; m3v = t3;
                    l0 *= sc0; l1 *= sc1; l2 *= sc2; l3 *= sc3;
                    acc0[0] *= sc0; acc0[1] *= sc1; acc0[2] *= sc2; acc0[3] *= sc3;
                    acc1[0] *= sc0; acc1[1] *= sc1; acc1[2] *= sc2; acc1[3] *= sc3;
                }
                float p00 = __expf(s0[0] - m0v), p01 = __expf(s0[1] - m1v);
                float p02 = __expf(s0[2] - m2v), p03 = __expf(s0[3] - m3v);
                float p10 = __expf(s1[0] - m0v), p11 = __expf(s1[1] - m1v);
                float p12 = __expf(s1[2] - m2v), p13 = __expf(s1[3] - m3v);
                l0 += p00 + p10; l1 += p01 + p11; l2 += p02 + p12; l3 += p03 + p13;

                u16* pw = &sh.a.Plds[w][0][lq][lr];
                pw[0 * 64] = b16(p00); pw[1 * 64] = b16(p01);
                pw[2 * 64] = b16(p02); pw[3 * 64] = b16(p03);
                pw[4 * 64] = b16(p10); pw[5 * 64] = b16(p11);
                pw[6 * 64] = b16(p12); pw[7 * 64] = b16(p13);

                const bf16x8 pa = *(const bf16x8*)&sh.a.Plds[w][(lq >> 1) * 4 + (lr & 3)][lr >> 2][(lq & 1) * 8];
                acc0 = __builtin_amdgcn_mfma_f32_16x16x32_bf16(pa, cv0, acc0, 0, 0, 0);
                acc1 = __builtin_amdgcn_mfma_f32_16x16x32_bf16(pa, cv1, acc1, 0, 0, 0);

                cur = (cur == 2) ? 0 : cur + 1;
                nxt = (nxt == 2) ? 0 : nxt + 1;
            }
#undef STAGE
#undef KVLOAD

            RSUM(l0) RSUM(l1) RSUM(l2) RSUM(l3)
            const float rr[4] = {1.0f / l0, 1.0f / l1, 1.0f / l2, 1.0f / l3};
            const f32x4 a0 = acc0, a1 = acc1;

            const u16* Gb = Gw + (size_t)(b * N_ + qb + w * 16 + lq * 4) * CIN + h * CH + lr;
            u16* Ob = Owg + (size_t)(b * N_ + qb + w * 16 + lq * 4) * CIN + h * CH + lr;
#pragma unroll
            for (int r = 0; r < 4; r++) {
                const float g0 = bf2f(Gb[r * CIN]), g1 = bf2f(Gb[r * CIN + 16]);
                Ob[r * CIN]      = b16(a0[r] * rr[r] * g0);
                Ob[r * CIN + 16] = b16(a1[r] * rr[r] * g1);
            }
        } else {
            // ---------------- stage 3: output projection ----------------
            stage = 3;
            wait_done(&ctr[3], NIT2);
            const int o = item - IT3;
            const int y = o >> 2, x = o & 3;
            const int m0 = y * 64 + w * 16, n0 = x * 64;
            const u16* Arows = Owg + (size_t)(y * 64) * CIN;
            const u16* Brows = WoT + (size_t)(x * 64) * CIN;
            f32x4 acc[4] = {{0,0,0,0},{0,0,0,0},{0,0,0,0},{0,0,0,0}};

            stg_b16(Arows, sh.g.At, tid);
            stg_b16(Brows, sh.g.Bt, tid);
            __syncthreads();
            bf16x8 ra[4], rb[4];
            ld1_b16(Arows, ra, tid);
            ld1_b16(Brows, rb, tid);
            compute_phase(sh.g.At, sh.g.Bt, w, lr, lq, acc);
            __syncthreads();
            wr1_b16(ra, sh.g.At, tid);
            wr1_b16(rb, sh.g.Bt, tid);
            __syncthreads();
            compute_phase(sh.g.At, sh.g.Bt, w, lr, lq, acc);

#pragma unroll
            for (int nt = 0; nt < 4; nt++) {
                const float bb = bo[n0 + nt * 16 + lr];
#pragma unroll
                for (int r = 0; r < 4; r++)
                    out[(size_t)(m0 + lq * 4 + r) * CIN + n0 + nt * 16 + lr] = acc[nt][r] + bb;
            }
        }

        // release: wg-barrier establishes HB from all threads' stores to
        // thread0's agent-scope release RMW (also drains vmcnt/outstanding DMA)
        __syncthreads();
        if (tid == 0 && stage < 3)
            __hip_atomic_fetch_add(&ctr[1 + stage], 1u, __ATOMIC_RELEASE, __HIP_MEMORY_SCOPE_AGENT);
    }
}

// ---------------------------------------------------------------------------
extern "C" void kernel_launch(void* const* d_in, const int* in_sizes, int n_in,
                              void* d_out, int out_size, void* d_ws, size_t ws_size,
                              hipStream_t stream)
{
    const float* qx   = (const float*)d_in[0];
    const float* kvx  = (const float*)d_in[1];
    const float* bias = (const float*)d_in[2];
    const float* Wq = (const float*)d_in[3];
    const float* Wk = (const float*)d_in[4];
    const float* Wv = (const float*)d_in[5];
    const float* Wg = (const float*)d_in[6];
    const float* bg = (const float*)d_in[7];
    const float* Wo = (const float*)d_in[8];
    const float* bo = (const float*)d_in[9];
    float* out = (float*)d_out;

    char* ws = (char*)d_ws;
    const size_t SZB = (size_t)B_ * N_ * CIN * 2;   // 2 MB per bf16 [4096][256]
    u16* Qw   = (u16*)(ws + 2 * SZB);
    u16* Kw   = (u16*)(ws + 3 * SZB);
    u16* Vt   = (u16*)(ws + 4 * SZB);
    u16* Gw   = (u16*)(ws + 5 * SZB);
    u16* Owg  = (u16*)(ws + 6 * SZB);
    const size_t WSZ = (size_t)CIN * CIN * 2;       // 128 KB per bf16 weight
    u16* WqT = (u16*)(ws + 7 * SZB + 0 * WSZ);
    u16* WkT = (u16*)(ws + 7 * SZB + 1 * WSZ);
    u16* WvT = (u16*)(ws + 7 * SZB + 2 * WSZ);
    u16* WgT = (u16*)(ws + 7 * SZB + 3 * WSZ);
    u16* WoT = (u16*)(ws + 7 * SZB + 4 * WSZ);
    unsigned* ctr = (unsigned*)(ws + 7 * SZB + 5 * WSZ);   // 64 B queue/done counters

    hipMemsetAsync(ctr, 0, 64, stream);
    mega_kernel<<<dim3(1024), 256, 0, stream>>>(qx, kvx, bias, Wq, Wk, Wv, Wg,
                                                bg, Wo, bo,
                                                WqT, WkT, WvT, WgT, WoT,
                                                Qw, Kw, Vt, Gw, Owg, out, ctr);
}

// Round 5
// 130.724 us; speedup vs baseline: 3.1665x; 3.1665x over previous
//
#include <hip/hip_runtime.h>
#include <hip/hip_bf16.h>

#define B_   2
#define N_   2048
#define CIN  256
#define NH   8
#define CH   32

typedef unsigned short u16;
typedef __attribute__((ext_vector_type(4))) float f32x4;
typedef __bf16 bf16x8 __attribute__((ext_vector_type(8)));
typedef u16 u16x4 __attribute__((ext_vector_type(4)));
typedef u16 u16x8 __attribute__((ext_vector_type(8)));

static __device__ __forceinline__ u16 b16(float f) {
    __bf16 h = (__bf16)f;
    union { __bf16 h; u16 u; } c; c.h = h; return c.u;
}
static __device__ __forceinline__ float bf2f(u16 u) {
    union { unsigned u; float f; } c; c.u = ((unsigned)u) << 16; return c.f;
}
static __device__ __forceinline__ float sigmoidf_(float x) {
    return 1.0f / (1.0f + __expf(-x));
}
static __device__ __forceinline__ void gload_lds16(const void* g, void* lds) {
    __builtin_amdgcn_global_load_lds(
        (const __attribute__((address_space(1))) unsigned int*)g,
        (__attribute__((address_space(3))) unsigned int*)lds, 16, 0, 0);
}

// ---------------------------------------------------------------------------
// Two dispatches, ZERO intra-kernel waiting (round-4 lesson: spin loops with
// acquire loads invalidate co-resident waves' L1 -> 4x collapse).
//  D1 proj_kernel : projections with SELF-TRANSPOSED weights (no prep kernel,
//                   no stage dependency). Tail blocks transpose Wo + zero ctrs.
//  D2 attn_out    : flash attention; the 8th (last) head-block of each 64-row
//                   block runs the out-projection inline (release/acquire
//                   fetch_add handoff -- never spins; validated in round 4).
// ---------------------------------------------------------------------------
#define LDW 136   // padded LDS row (u16): 272B; 272%128=16B -> conflict-free b128 reads

// ---- staged GEMM-tile helpers (64 rows x 128 k per phase) ----
static __device__ __forceinline__ u16x8 cvt8(float4 a, float4 b) {
    u16x8 o;
    o[0] = b16(a.x); o[1] = b16(a.y); o[2] = b16(a.z); o[3] = b16(a.w);
    o[4] = b16(b.x); o[5] = b16(b.y); o[6] = b16(b.z); o[7] = b16(b.w);
    return o;
}
static __device__ __forceinline__ void stg_b16(const u16* __restrict__ src, u16 (*dst)[LDW], int tid) {
#pragma unroll
    for (int i = 0; i < 4; i++) {
        const int e = tid + 256 * i, row = e >> 4, c = e & 15;
        *(bf16x8*)&dst[row][c * 8] = *(const bf16x8*)(src + (size_t)row * CIN + c * 8);
    }
}
static __device__ __forceinline__ void ld1_b16(const u16* __restrict__ src, bf16x8 r[4], int tid) {
#pragma unroll
    for (int i = 0; i < 4; i++) {
        const int e = tid + 256 * i, row = e >> 4, c = e & 15;
        r[i] = *(const bf16x8*)(src + (size_t)row * CIN + 128 + c * 8);
    }
}
static __device__ __forceinline__ void wr1_b16(const bf16x8 r[4], u16 (*dst)[LDW], int tid) {
#pragma unroll
    for (int i = 0; i < 4; i++) {
        const int e = tid + 256 * i, row = e >> 4, c = e & 15;
        *(bf16x8*)&dst[row][c * 8] = r[i];
    }
}
static __device__ __forceinline__ void stg_f32(const float* __restrict__ src, u16 (*dst)[LDW], int tid) {
#pragma unroll
    for (int i = 0; i < 4; i++) {
        const int e = tid + 256 * i, row = e >> 4, c = e & 15;
        const float* s = src + (size_t)row * CIN + c * 8;
        *(u16x8*)&dst[row][c * 8] = cvt8(*(const float4*)s, *(const float4*)(s + 4));
    }
}
// transpose-stage a 64-col slab of f32 W[k][n] into dst[n][k] bf16.
// lane mapping: 16 lanes read 16 consecutive n (64B coalesced); LDS write
// banks = n*68%32 with n stepping by 1 across lanes -> 2-way max (free).
static __device__ __forceinline__ void trn_stage(const float* __restrict__ W, int n0,
                                                 u16 (*dst)[LDW], int tid, int kbase, float s) {
#pragma unroll
    for (int i = 0; i < 8; i++) {
        const int e = tid + 256 * i;     // 0..2047
        const int kl = e >> 4;           // 0..127
        const int nb = e & 15;           // 0..15
#pragma unroll
        for (int j = 0; j < 4; j++) {
            float v = W[(size_t)(kbase + kl) * CIN + n0 + nb + j * 16];
            dst[nb + j * 16][kl] = b16(v * s);
        }
    }
}
static __device__ __forceinline__ void compute_phase(
    const u16 (*At)[LDW], const u16 (*Bt)[LDW], int w, int lr, int lq, f32x4 acc[4])
{
#pragma unroll
    for (int kk = 0; kk < 128; kk += 32) {
        bf16x8 af = *(const bf16x8*)&At[w * 16 + lr][kk + lq * 8];
#pragma unroll
        for (int nt = 0; nt < 4; nt++) {
            bf16x8 bf = *(const bf16x8*)&Bt[nt * 16 + lr][kk + lq * 8];
            acc[nt] = __builtin_amdgcn_mfma_f32_16x16x32_bf16(af, bf, acc[nt], 0, 0, 0);
        }
    }
}

// ---------------------------------------------------------------------------
// D1: blocks [0,1024) projections (z=0 Q, z=1 K, z=2 Vt, z=3 G);
//     blocks [1024,1040) Wo transpose (block 1024 also zeroes rctr).
// Weight B-tiles are self-transposed from f32 (b16(v*s) -- bit-identical to
// the old prep+copy path). X A-tiles staged straight from f32 (validated r4).
// ---------------------------------------------------------------------------
__global__ __launch_bounds__(256, 4)
void proj_kernel(const float* __restrict__ qx, const float* __restrict__ kvx,
                 const float* __restrict__ Wq, const float* __restrict__ Wk,
                 const float* __restrict__ Wv, const float* __restrict__ Wg,
                 const float* __restrict__ bgv, const float* __restrict__ Wo,
                 u16* __restrict__ Qw, u16* __restrict__ Kw,
                 u16* __restrict__ Vt, u16* __restrict__ Gw,
                 u16* __restrict__ WoT, unsigned* __restrict__ rctr)
{
    const int flat = blockIdx.x;
    const int tid = threadIdx.x, w = tid >> 6, l = tid & 63, lr = l & 15, lq = l >> 4;
    __shared__ union {
        float T[64][65];
        struct { u16 At[64][LDW]; u16 Bt[64][LDW]; } g;
    } sh;

    if (flat >= 1024) {
        if (flat == 1024 && tid < 64) rctr[tid] = 0;   // handoff ctrs for D2
        const int t16 = flat - 1024;
        const int k0 = (t16 & 3) * 64, n0 = (t16 >> 2) * 64;
        const int a = tid >> 4, c4 = (tid & 15) * 4;
#pragma unroll
        for (int i = 0; i < 4; i++) {
            float4 v = *(const float4*)&Wo[(size_t)(k0 + a + i * 16) * CIN + n0 + c4];
            sh.T[a + i * 16][c4 + 0] = v.x; sh.T[a + i * 16][c4 + 1] = v.y;
            sh.T[a + i * 16][c4 + 2] = v.z; sh.T[a + i * 16][c4 + 3] = v.w;
        }
        __syncthreads();
#pragma unroll
        for (int i = 0; i < 4; i++) {
            const int nr = a + i * 16;
            u16x4 o;
            o[0] = b16(sh.T[c4 + 0][nr]); o[1] = b16(sh.T[c4 + 1][nr]);
            o[2] = b16(sh.T[c4 + 2][nr]); o[3] = b16(sh.T[c4 + 3][nr]);
            *(u16x4*)&WoT[(size_t)(n0 + nr) * CIN + k0 + c4] = o;
        }
        return;
    }

    const int z = flat >> 8, y = (flat >> 2) & 63, x = flat & 3;
    const float* Xf = ((z == 0 || z == 3) ? qx : kvx) + (size_t)(y * 64) * CIN;
    const float* Wz = (z == 0) ? Wq : (z == 1) ? Wk : (z == 2) ? Wv : Wg;
    const float scale = (z == 0) ? 0.17677669529663687f : 1.0f;
    const int n0w = x * 64;
    u16 (*Xt)[LDW] = (z == 2) ? sh.g.Bt : sh.g.At;   // straight-staged X
    u16 (*Wt)[LDW] = (z == 2) ? sh.g.At : sh.g.Bt;   // transposed weight

    f32x4 acc[4] = {{0,0,0,0},{0,0,0,0},{0,0,0,0},{0,0,0,0}};

    stg_f32(Xf, Xt, tid);
    trn_stage(Wz, n0w, Wt, tid, 0, scale);
    __syncthreads();
    float4 rx[8];                                     // X phase-1 async split
#pragma unroll
    for (int i = 0; i < 4; i++) {
        const int e = tid + 256 * i, row = e >> 4, c = e & 15;
        const float* s = Xf + (size_t)row * CIN + 128 + c * 8;
        rx[2 * i] = *(const float4*)s; rx[2 * i + 1] = *(const float4*)(s + 4);
    }
    compute_phase(sh.g.At, sh.g.Bt, w, lr, lq, acc);
    __syncthreads();
#pragma unroll
    for (int i = 0; i < 4; i++) {
        const int e = tid + 256 * i, row = e >> 4, c = e & 15;
        *(u16x8*)&Xt[row][c * 8] = cvt8(rx[2 * i], rx[2 * i + 1]);
    }
    trn_stage(Wz, n0w, Wt, tid, 128, scale);          // L2-hot by now
    __syncthreads();
    compute_phase(sh.g.At, sh.g.Bt, w, lr, lq, acc);

    if (z != 2) {
        const int m0 = y * 64 + w * 16, n0 = x * 64;
        if (z == 3) {
#pragma unroll
            for (int nt = 0; nt < 4; nt++) {
                const int col = n0 + nt * 16 + lr;
                const float bb = bgv[col];
#pragma unroll
                for (int r = 0; r < 4; r++)
                    Gw[(size_t)(m0 + lq * 4 + r) * CIN + col] = b16(sigmoidf_(acc[nt][r] + bb));
            }
        } else {
            u16* D = (z == 0) ? Qw : Kw;
#pragma unroll
            for (int nt = 0; nt < 4; nt++)
#pragma unroll
                for (int r = 0; r < 4; r++)
                    D[(size_t)(m0 + lq * 4 + r) * CIN + n0 + nt * 16 + lr] = b16(acc[nt][r]);
        }
    } else {
        const int c0 = x * 64 + w * 16;
        const int n0g = y * 64;
        const int bb_ = n0g >> 11, nl0 = n0g & (N_ - 1);
#pragma unroll
        for (int nt = 0; nt < 4; nt++)
#pragma unroll
            for (int r = 0; r < 4; r++)
                Vt[((size_t)bb_ * CIN + c0 + lq * 4 + r) * N_ + nl0 + nt * 16 + lr] = b16(acc[nt][r]);
    }
}

// ---------------------------------------------------------------------------
// D2: flash attention (round-3 barrier-free structure, verbatim) + fused
// out-projection by the LAST of the 8 head-blocks per 64-row block.
// ---------------------------------------------------------------------------
#define RMAX(x) { x = fmaxf(x, __shfl_xor(x, 1)); x = fmaxf(x, __shfl_xor(x, 2)); \
                  x = fmaxf(x, __shfl_xor(x, 4)); x = fmaxf(x, __shfl_xor(x, 8)); }
#define RSUM(x) { x += __shfl_xor(x, 1); x += __shfl_xor(x, 2); \
                  x += __shfl_xor(x, 4); x += __shfl_xor(x, 8); }

__global__ __launch_bounds__(256)
void attn_out_kernel(const u16* __restrict__ Qw, const u16* __restrict__ Kw,
                     const u16* __restrict__ Vt, const float* __restrict__ bias,
                     const u16* __restrict__ Gw, const u16* __restrict__ WoT,
                     const float* __restrict__ bo,
                     u16* __restrict__ Owg, float* __restrict__ out,
                     unsigned* __restrict__ rctr)
{
    const int bid = blockIdx.x;
    const int h = bid & 7, qt = (bid >> 3) & 31, b = bid >> 8;
    const int tid = threadIdx.x;
    const int w = tid >> 6, l = tid & 63, lr = l & 15, lq = l >> 4;
    const int qb = qt * 64;

    __shared__ union {
        struct { float Btl[4][3][16][32]; u16 Plds[4][8][4][16]; } a;  // attn (28 KB)
        struct { u16 At[64][LDW]; u16 Bt[64][LDW]; } g;                // out  (34.8 KB)
    } sh;
    __shared__ unsigned s_prev;

    const bf16x8 qf = *(const bf16x8*)(Qw + (size_t)(b * N_ + qb + w * 16 + lr) * CIN + h * CH + lq * 8);
    const u16* Kb = Kw + (size_t)(b * N_ + lr) * CIN + h * CH + lq * 8;
    const u16* Vb = Vt + (size_t)((b * NH + h) * CH + lr) * N_ + lq * 8;
    const float* biasW = bias + ((size_t)(b * NH + h) * N_ + qb + w * 16) * N_;
    const float* gl0 = biasW + (size_t)(l >> 3) * N_ + (l & 7) * 4;
    const float* gl1 = biasW + (size_t)(8 + (l >> 3)) * N_ + (l & 7) * 4;

#define STAGE(TT, BI) { \
    gload_lds16(gl0 + (size_t)(TT) * 32, &sh.a.Btl[w][BI][0][0]); \
    gload_lds16(gl1 + (size_t)(TT) * 32, &sh.a.Btl[w][BI][8][0]); }
#define KVLOAD(K) { kf0 = *(const bf16x8*)(Kb + (size_t)(K) * CIN); \
                    kf1 = *(const bf16x8*)(Kb + (size_t)((K) + 16) * CIN); \
                    vf0 = *(const bf16x8*)(Vb + (K)); \
                    vf1 = *(const bf16x8*)(Vb + 16 * N_ + (K)); }

    f32x4 acc0 = {0.f, 0.f, 0.f, 0.f}, acc1 = {0.f, 0.f, 0.f, 0.f};
    float m0v = 8.f, m1v = 8.f, m2v = 8.f, m3v = 8.f;   // defer-max init
    float l0 = 0.f, l1 = 0.f, l2 = 0.f, l3 = 0.f;
    bf16x8 kf0, kf1, vf0, vf1;

    STAGE(0, 0)
    __builtin_amdgcn_sched_barrier(0);
    KVLOAD(0)
    __builtin_amdgcn_sched_barrier(0);
    STAGE(1, 1)
    __builtin_amdgcn_sched_barrier(0);

    int cur = 0, nxt = 2;
    for (int t = 0; t < 64; t++) {
        // outstanding: [S(t):2][K(t):4][S(t+1):2] -> keep newest 2
        asm volatile("s_waitcnt vmcnt(2)" ::: "memory");
        const bf16x8 ck0 = kf0, ck1 = kf1, cv0 = vf0, cv1 = vf1;
        KVLOAD(((t + 1) & 63) * 32)
        __builtin_amdgcn_sched_barrier(0);
        STAGE((t + 2) & 63, nxt)
        __builtin_amdgcn_sched_barrier(0);

        const float* bt = &sh.a.Btl[w][cur][lq * 4][0];
        f32x4 c0, c1;
        c0[0] = bt[0 * 32 + lr];      c0[1] = bt[1 * 32 + lr];
        c0[2] = bt[2 * 32 + lr];      c0[3] = bt[3 * 32 + lr];
        c1[0] = bt[0 * 32 + 16 + lr]; c1[1] = bt[1 * 32 + 16 + lr];
        c1[2] = bt[2 * 32 + 16 + lr]; c1[3] = bt[3 * 32 + 16 + lr];

        f32x4 s0 = __builtin_amdgcn_mfma_f32_16x16x32_bf16(qf, ck0, c0, 0, 0, 0);
        f32x4 s1 = __builtin_amdgcn_mfma_f32_16x16x32_bf16(qf, ck1, c1, 0, 0, 0);

        float pm0 = fmaxf(s0[0], s1[0]);
        float pm1 = fmaxf(s0[1], s1[1]);
        float pm2 = fmaxf(s0[2], s1[2]);
        float pm3 = fmaxf(s0[3], s1[3]);
        bool ev = (pm0 > m0v) || (pm1 > m1v) || (pm2 > m2v) || (pm3 > m3v);
        if (__any(ev)) {
            RMAX(pm0) RMAX(pm1) RMAX(pm2) RMAX(pm3)
            float t0 = fmaxf(m0v, pm0), t1 = fmaxf(m1v, pm1);
            float t2 = fmaxf(m2v, pm2), t3 = fmaxf(m3v, pm3);
            float sc0 = __expf(m0v - t0), sc1 = __expf(m1v - t1);
            float sc2 = __expf(m2v - t2), sc3 = __expf(m3v - t3);
            m0v = t0; m1v = t1; m2v = t2; m3v = t3;
            l0 *= sc0; l1 *= sc1; l2 *= sc2; l3 *= sc3;
            acc0[0] *= sc0; acc0[1] *= sc1; acc0[2] *= sc2; acc0[3] *= sc3;
            acc1[0] *= sc0; acc1[1] *= sc1; acc1[2] *= sc2; acc1[3] *= sc3;
        }
        float p00 = __expf(s0[0] - m0v), p01 = __expf(s0[1] - m1v);
        float p02 = __expf(s0[2] - m2v), p03 = __expf(s0[3] - m3v);
        float p10 = __expf(s1[0] - m0v), p11 = __expf(s1[1] - m1v);
        float p12 = __expf(s1[2] - m2v), p13 = __expf(s1[3] - m3v);
        l0 += p00 + p10; l1 += p01 + p11; l2 += p02 + p12; l3 += p03 + p13;

        u16* pw = &sh.a.Plds[w][0][lq][lr];
        pw[0 * 64] = b16(p00); pw[1 * 64] = b16(p01);
        pw[2 * 64] = b16(p02); pw[3 * 64] = b16(p03);
        pw[4 * 64] = b16(p10); pw[5 * 64] = b16(p11);
        pw[6 * 64] = b16(p12); pw[7 * 64] = b16(p13);

        const bf16x8 pa = *(const bf16x8*)&sh.a.Plds[w][(lq >> 1) * 4 + (lr & 3)][lr >> 2][(lq & 1) * 8];
        acc0 = __builtin_amdgcn_mfma_f32_16x16x32_bf16(pa, cv0, acc0, 0, 0, 0);
        acc1 = __builtin_amdgcn_mfma_f32_16x16x32_bf16(pa, cv1, acc1, 0, 0, 0);

        cur = (cur == 2) ? 0 : cur + 1;
        nxt = (nxt == 2) ? 0 : nxt + 1;
    }
#undef STAGE
#undef KVLOAD

    RSUM(l0) RSUM(l1) RSUM(l2) RSUM(l3)
    const float rr[4] = {1.0f / l0, 1.0f / l1, 1.0f / l2, 1.0f / l3};
    const f32x4 a0 = acc0, a1 = acc1;

    const u16* Gb = Gw + (size_t)(b * N_ + qb + w * 16 + lq * 4) * CIN + h * CH + lr;
    u16* Ob = Owg + (size_t)(b * N_ + qb + w * 16 + lq * 4) * CIN + h * CH + lr;
#pragma unroll
    for (int r = 0; r < 4; r++) {
        const float g0 = bf2f(Gb[r * CIN]), g1 = bf2f(Gb[r * CIN + 16]);
        Ob[r * CIN]      = b16(a0[r] * rr[r] * g0);
        Ob[r * CIN + 16] = b16(a1[r] * rr[r] * g1);
    }

    // ---- handoff: 8 producers per 64-row block; last one runs out-proj ----
    asm volatile("s_waitcnt vmcnt(0)" ::: "memory");   // drain Owg stores + DMA
    __syncthreads();
    if (tid == 0)
        s_prev = __hip_atomic_fetch_add(&rctr[b * 32 + qt], 1u,
                                        __ATOMIC_ACQ_REL, __HIP_MEMORY_SCOPE_AGENT);
    __syncthreads();
    if (s_prev != 7) return;                           // not last: done (no spin)

    const int y = b * 32 + qt;
    const u16* Arows = Owg + (size_t)(y * 64) * CIN;
    for (int x = 0; x < 4; x++) {
        const u16* Brows = WoT + (size_t)(x * 64) * CIN;
        f32x4 acc[4] = {{0,0,0,0},{0,0,0,0},{0,0,0,0},{0,0,0,0}};
        stg_b16(Arows, sh.g.At, tid);
        stg_b16(Brows, sh.g.Bt, tid);
        __syncthreads();
        bf16x8 ra[4], rb[4];
        ld1_b16(Arows, ra, tid);
        ld1_b16(Brows, rb, tid);
        compute_phase(sh.g.At, sh.g.Bt, w, lr, lq, acc);
        __syncthreads();
        wr1_b16(ra, sh.g.At, tid);
        wr1_b16(rb, sh.g.Bt, tid);
        __syncthreads();
        compute_phase(sh.g.At, sh.g.Bt, w, lr, lq, acc);

        const int m0 = y * 64 + w * 16, n0o = x * 64;
#pragma unroll
        for (int nt = 0; nt < 4; nt++) {
            const float bb = bo[n0o + nt * 16 + lr];
#pragma unroll
            for (int r = 0; r < 4; r++)
                out[(size_t)(m0 + lq * 4 + r) * CIN + n0o + nt * 16 + lr] = acc[nt][r] + bb;
        }
        __syncthreads();                               // WAR before next x restage
    }
}

// ---------------------------------------------------------------------------
extern "C" void kernel_launch(void* const* d_in, const int* in_sizes, int n_in,
                              void* d_out, int out_size, void* d_ws, size_t ws_size,
                              hipStream_t stream)
{
    const float* qx   = (const float*)d_in[0];
    const float* kvx  = (const float*)d_in[1];
    const float* bias = (const float*)d_in[2];
    const float* Wq = (const float*)d_in[3];
    const float* Wk = (const float*)d_in[4];
    const float* Wv = (const float*)d_in[5];
    const float* Wg = (const float*)d_in[6];
    const float* bg = (const float*)d_in[7];
    const float* Wo = (const float*)d_in[8];
    const float* bo = (const float*)d_in[9];
    float* out = (float*)d_out;

    char* ws = (char*)d_ws;
    const size_t SZB = (size_t)B_ * N_ * CIN * 2;   // 2 MB per bf16 [4096][256]
    u16* Qw   = (u16*)(ws + 2 * SZB);
    u16* Kw   = (u16*)(ws + 3 * SZB);
    u16* Vt   = (u16*)(ws + 4 * SZB);
    u16* Gw   = (u16*)(ws + 5 * SZB);
    u16* Owg  = (u16*)(ws + 6 * SZB);
    const size_t WSZ = (size_t)CIN * CIN * 2;       // 128 KB per bf16 weight
    u16* WoT  = (u16*)(ws + 7 * SZB + 4 * WSZ);
    unsigned* rctr = (unsigned*)(ws + 7 * SZB + 5 * WSZ);  // 64 row-block ctrs

    proj_kernel<<<dim3(1040), 256, 0, stream>>>(qx, kvx, Wq, Wk, Wv, Wg, bg, Wo,
                                                Qw, Kw, Vt, Gw, WoT, rctr);
    attn_out_kernel<<<dim3(512), 256, 0, stream>>>(Qw, Kw, Vt, bias, Gw, WoT, bo,
                                                   Owg, out, rctr);
}

// Round 6
// 118.474 us; speedup vs baseline: 3.4939x; 1.1034x over previous
//
#include <hip/hip_runtime.h>
#include <hip/hip_bf16.h>

#define B_   2
#define N_   2048
#define CIN  256
#define NH   8
#define CH   32

typedef unsigned short u16;
typedef __attribute__((ext_vector_type(4))) float f32x4;
typedef __bf16 bf16x8 __attribute__((ext_vector_type(8)));
typedef u16 u16x4 __attribute__((ext_vector_type(4)));
typedef u16 u16x8 __attribute__((ext_vector_type(8)));

static __device__ __forceinline__ u16 b16(float f) {
    __bf16 h = (__bf16)f;
    union { __bf16 h; u16 u; } c; c.h = h; return c.u;
}
static __device__ __forceinline__ float bf2f(u16 u) {
    union { unsigned u; float f; } c; c.u = ((unsigned)u) << 16; return c.f;
}
static __device__ __forceinline__ float sigmoidf_(float x) {
    return 1.0f / (1.0f + __expf(-x));
}
static __device__ __forceinline__ void gload_lds16(const void* g, void* lds) {
    __builtin_amdgcn_global_load_lds(
        (const __attribute__((address_space(1))) unsigned int*)g,
        (__attribute__((address_space(3))) unsigned int*)lds, 16, 0, 0);
}

// ---------------------------------------------------------------------------
// 3 dispatches, no cross-block sync:
//  D1 proj_kernel: projections w/ self-transposed weights (+Wo transpose tail)
//  D2 attn_kernel: flash attention, KEY-SPLIT 2x per block (4096 waves chip-
//     wide vs 2048 before -- round-5 counters showed latency-bound 2 w/SIMD),
//     in-LDS partial-softmax merge, bias source-XOR swizzle (4-way -> 2-way
//     free bank pattern on C-operand reads).
//  D3 out_mfma: staged 64x64 GEMM (round-3 validated).
// ---------------------------------------------------------------------------
#define LDW 136   // padded LDS row (u16): 272B; 272%128=16B -> conflict-free b128

static __device__ __forceinline__ u16x8 cvt8(float4 a, float4 b) {
    u16x8 o;
    o[0] = b16(a.x); o[1] = b16(a.y); o[2] = b16(a.z); o[3] = b16(a.w);
    o[4] = b16(b.x); o[5] = b16(b.y); o[6] = b16(b.z); o[7] = b16(b.w);
    return o;
}
static __device__ __forceinline__ void stg_b16(const u16* __restrict__ src, u16 (*dst)[LDW], int tid) {
#pragma unroll
    for (int i = 0; i < 4; i++) {
        const int e = tid + 256 * i, row = e >> 4, c = e & 15;
        *(bf16x8*)&dst[row][c * 8] = *(const bf16x8*)(src + (size_t)row * CIN + c * 8);
    }
}
static __device__ __forceinline__ void ld1_b16(const u16* __restrict__ src, bf16x8 r[4], int tid) {
#pragma unroll
    for (int i = 0; i < 4; i++) {
        const int e = tid + 256 * i, row = e >> 4, c = e & 15;
        r[i] = *(const bf16x8*)(src + (size_t)row * CIN + 128 + c * 8);
    }
}
static __device__ __forceinline__ void wr1_b16(const bf16x8 r[4], u16 (*dst)[LDW], int tid) {
#pragma unroll
    for (int i = 0; i < 4; i++) {
        const int e = tid + 256 * i, row = e >> 4, c = e & 15;
        *(bf16x8*)&dst[row][c * 8] = r[i];
    }
}
static __device__ __forceinline__ void stg_f32(const float* __restrict__ src, u16 (*dst)[LDW], int tid) {
#pragma unroll
    for (int i = 0; i < 4; i++) {
        const int e = tid + 256 * i, row = e >> 4, c = e & 15;
        const float* s = src + (size_t)row * CIN + c * 8;
        *(u16x8*)&dst[row][c * 8] = cvt8(*(const float4*)s, *(const float4*)(s + 4));
    }
}
static __device__ __forceinline__ void trn_stage(const float* __restrict__ W, int n0,
                                                 u16 (*dst)[LDW], int tid, int kbase, float s) {
#pragma unroll
    for (int i = 0; i < 8; i++) {
        const int e = tid + 256 * i;
        const int kl = e >> 4, nb = e & 15;
#pragma unroll
        for (int j = 0; j < 4; j++) {
            float v = W[(size_t)(kbase + kl) * CIN + n0 + nb + j * 16];
            dst[nb + j * 16][kl] = b16(v * s);
        }
    }
}
static __device__ __forceinline__ void compute_phase(
    const u16 (*At)[LDW], const u16 (*Bt)[LDW], int w, int lr, int lq, f32x4 acc[4])
{
#pragma unroll
    for (int kk = 0; kk < 128; kk += 32) {
        bf16x8 af = *(const bf16x8*)&At[w * 16 + lr][kk + lq * 8];
#pragma unroll
        for (int nt = 0; nt < 4; nt++) {
            bf16x8 bf = *(const bf16x8*)&Bt[nt * 16 + lr][kk + lq * 8];
            acc[nt] = __builtin_amdgcn_mfma_f32_16x16x32_bf16(af, bf, acc[nt], 0, 0, 0);
        }
    }
}

// ---------------------------------------------------------------------------
// D1: blocks [0,1024) projections (z=0 Q,1 K,2 Vt,3 G); [1024,1040) Wo^T
// ---------------------------------------------------------------------------
__global__ __launch_bounds__(256, 4)
void proj_kernel(const float* __restrict__ qx, const float* __restrict__ kvx,
                 const float* __restrict__ Wq, const float* __restrict__ Wk,
                 const float* __restrict__ Wv, const float* __restrict__ Wg,
                 const float* __restrict__ bgv, const float* __restrict__ Wo,
                 u16* __restrict__ Qw, u16* __restrict__ Kw,
                 u16* __restrict__ Vt, u16* __restrict__ Gw,
                 u16* __restrict__ WoT)
{
    const int flat = blockIdx.x;
    const int tid = threadIdx.x, w = tid >> 6, l = tid & 63, lr = l & 15, lq = l >> 4;
    __shared__ union {
        float T[64][65];
        struct { u16 At[64][LDW]; u16 Bt[64][LDW]; } g;
    } sh;

    if (flat >= 1024) {
        const int t16 = flat - 1024;
        const int k0 = (t16 & 3) * 64, n0 = (t16 >> 2) * 64;
        const int a = tid >> 4, c4 = (tid & 15) * 4;
#pragma unroll
        for (int i = 0; i < 4; i++) {
            float4 v = *(const float4*)&Wo[(size_t)(k0 + a + i * 16) * CIN + n0 + c4];
            sh.T[a + i * 16][c4 + 0] = v.x; sh.T[a + i * 16][c4 + 1] = v.y;
            sh.T[a + i * 16][c4 + 2] = v.z; sh.T[a + i * 16][c4 + 3] = v.w;
        }
        __syncthreads();
#pragma unroll
        for (int i = 0; i < 4; i++) {
            const int nr = a + i * 16;
            u16x4 o;
            o[0] = b16(sh.T[c4 + 0][nr]); o[1] = b16(sh.T[c4 + 1][nr]);
            o[2] = b16(sh.T[c4 + 2][nr]); o[3] = b16(sh.T[c4 + 3][nr]);
            *(u16x4*)&WoT[(size_t)(n0 + nr) * CIN + k0 + c4] = o;
        }
        return;
    }

    const int z = flat >> 8, y = (flat >> 2) & 63, x = flat & 3;
    const float* Xf = ((z == 0 || z == 3) ? qx : kvx) + (size_t)(y * 64) * CIN;
    const float* Wz = (z == 0) ? Wq : (z == 1) ? Wk : (z == 2) ? Wv : Wg;
    const float scale = (z == 0) ? 0.17677669529663687f : 1.0f;
    const int n0w = x * 64;
    u16 (*Xt)[LDW] = (z == 2) ? sh.g.Bt : sh.g.At;
    u16 (*Wt)[LDW] = (z == 2) ? sh.g.At : sh.g.Bt;

    f32x4 acc[4] = {{0,0,0,0},{0,0,0,0},{0,0,0,0},{0,0,0,0}};

    stg_f32(Xf, Xt, tid);
    trn_stage(Wz, n0w, Wt, tid, 0, scale);
    __syncthreads();
    float4 rx[8];
#pragma unroll
    for (int i = 0; i < 4; i++) {
        const int e = tid + 256 * i, row = e >> 4, c = e & 15;
        const float* s = Xf + (size_t)row * CIN + 128 + c * 8;
        rx[2 * i] = *(const float4*)s; rx[2 * i + 1] = *(const float4*)(s + 4);
    }
    compute_phase(sh.g.At, sh.g.Bt, w, lr, lq, acc);
    __syncthreads();
#pragma unroll
    for (int i = 0; i < 4; i++) {
        const int e = tid + 256 * i, row = e >> 4, c = e & 15;
        *(u16x8*)&Xt[row][c * 8] = cvt8(rx[2 * i], rx[2 * i + 1]);
    }
    trn_stage(Wz, n0w, Wt, tid, 128, scale);
    __syncthreads();
    compute_phase(sh.g.At, sh.g.Bt, w, lr, lq, acc);

    if (z != 2) {
        const int m0 = y * 64 + w * 16, n0 = x * 64;
        if (z == 3) {
#pragma unroll
            for (int nt = 0; nt < 4; nt++) {
                const int col = n0 + nt * 16 + lr;
                const float bb = bgv[col];
#pragma unroll
                for (int r = 0; r < 4; r++)
                    Gw[(size_t)(m0 + lq * 4 + r) * CIN + col] = b16(sigmoidf_(acc[nt][r] + bb));
            }
        } else {
            u16* D = (z == 0) ? Qw : Kw;
#pragma unroll
            for (int nt = 0; nt < 4; nt++)
#pragma unroll
                for (int r = 0; r < 4; r++)
                    D[(size_t)(m0 + lq * 4 + r) * CIN + n0 + nt * 16 + lr] = b16(acc[nt][r]);
        }
    } else {
        const int c0 = x * 64 + w * 16;
        const int n0g = y * 64;
        const int bb_ = n0g >> 11, nl0 = n0g & (N_ - 1);
#pragma unroll
        for (int nt = 0; nt < 4; nt++)
#pragma unroll
            for (int r = 0; r < 4; r++)
                Vt[((size_t)bb_ * CIN + c0 + lq * 4 + r) * N_ + nl0 + nt * 16 + lr] = b16(acc[nt][r]);
    }
}

// ---------------------------------------------------------------------------
// D2: flash attention, key-split 2x.
// Block = (b, h, 32 q-rows). Wave w: q-half rp=w&1 (16 rows), key-half
// kh=w>>1 (1024 keys, 32 tiles). Same per-tile pipeline as round 3 (3-buf
// wave-private bias DMA, vmcnt(2), zero block barriers in the loop).
// Epilogue: waves 2,3 store (m,l,O) partials to their own LDS region; one
// barrier; waves 0,1 do the exact online-softmax merge + gate + Owg write.
// Bias LDS tile is XOR-swizzled at the SOURCE (rows with bit2 set swap
// 16-float halves) so C-operand reads are a balanced 2-way bank pattern.
// ---------------------------------------------------------------------------
#define RMAX(x) { x = fmaxf(x, __shfl_xor(x, 1)); x = fmaxf(x, __shfl_xor(x, 2)); \
                  x = fmaxf(x, __shfl_xor(x, 4)); x = fmaxf(x, __shfl_xor(x, 8)); }
#define RSUM(x) { x += __shfl_xor(x, 1); x += __shfl_xor(x, 2); \
                  x += __shfl_xor(x, 4); x += __shfl_xor(x, 8); }

__global__ __launch_bounds__(256)
void attn_kernel(const u16* __restrict__ Qw, const u16* __restrict__ Kw,
                 const u16* __restrict__ Vt, const float* __restrict__ bias,
                 const u16* __restrict__ Gw, u16* __restrict__ Owg)
{
    const int bid = blockIdx.x;
    const int h = bid & 7, qt = (bid >> 3) & 63, b = bid >> 9;
    const int tid = threadIdx.x;
    const int w = tid >> 6, l = tid & 63, lr = l & 15, lq = l >> 4;
    const int rp = w & 1, kh = w >> 1;
    const int qb = qt * 32;

    __shared__ __align__(16) float Btl[4][3][16][32];  // wave-private 3-buf bias (24 KB)
    __shared__ u16 Plds[4][8][4][16];                  // wave-private P staging (4 KB)

    const bf16x8 qf = *(const bf16x8*)(Qw + (size_t)(b * N_ + qb + rp * 16 + lr) * CIN + h * CH + lq * 8);
    const u16* Kb = Kw + (size_t)(b * N_ + kh * 1024 + lr) * CIN + h * CH + lq * 8;
    const u16* Vb = Vt + (size_t)((b * NH + h) * CH + lr) * N_ + kh * 1024 + lq * 8;
    const float* biasW = bias + ((size_t)(b * NH + h) * N_ + qb + rp * 16) * N_ + kh * 1024;

    // source-XOR swizzle: LDS granule g of row holds global granule g^(row&4)
    const int brow0 = l >> 3;                 // 0..7  (gl0 rows), gl1 = +8
    const int cswz = ((l & 7) ^ (((l >> 3) & 4) ? 4 : 0)) * 4;
    const float* gl0 = biasW + (size_t)brow0 * N_ + cswz;
    const float* gl1 = biasW + (size_t)(8 + brow0) * N_ + cswz;

#define STAGE(TT, BI) { \
    gload_lds16(gl0 + (size_t)(TT) * 32, &Btl[w][BI][0][0]); \
    gload_lds16(gl1 + (size_t)(TT) * 32, &Btl[w][BI][8][0]); }

#define KVLOAD(K) { kf0 = *(const bf16x8*)(Kb + (size_t)(K) * CIN); \
                    kf1 = *(const bf16x8*)(Kb + (size_t)((K) + 16) * CIN); \
                    vf0 = *(const bf16x8*)(Vb + (K)); \
                    vf1 = *(const bf16x8*)(Vb + 16 * N_ + (K)); }

    f32x4 acc0 = {0.f, 0.f, 0.f, 0.f}, acc1 = {0.f, 0.f, 0.f, 0.f};
    float m0v = 8.f, m1v = 8.f, m2v = 8.f, m3v = 8.f;   // defer-max init
    float l0 = 0.f, l1 = 0.f, l2 = 0.f, l3 = 0.f;
    bf16x8 kf0, kf1, vf0, vf1;

    STAGE(0, 0)
    __builtin_amdgcn_sched_barrier(0);
    KVLOAD(0)
    __builtin_amdgcn_sched_barrier(0);
    STAGE(1, 1)
    __builtin_amdgcn_sched_barrier(0);

    const int lrx = lr ^ ((lq & 1) << 4);      // read-side swizzle (row bit2 = lq&1)
    int cur = 0, nxt = 2;
    for (int t = 0; t < 32; t++) {
        // outstanding: [S(t):2][K(t):4][S(t+1):2] -> keep newest 2
        asm volatile("s_waitcnt vmcnt(2)" ::: "memory");
        const bf16x8 ck0 = kf0, ck1 = kf1, cv0 = vf0, cv1 = vf1;
        KVLOAD(((t + 1) & 31) * 32)
        __builtin_amdgcn_sched_barrier(0);
        STAGE((t + 2) & 31, nxt)
        __builtin_amdgcn_sched_barrier(0);

        const float* bt = &Btl[w][cur][lq * 4][0];
        f32x4 c0, c1;
        c0[0] = bt[0 * 32 + lrx];        c0[1] = bt[1 * 32 + lrx];
        c0[2] = bt[2 * 32 + lrx];        c0[3] = bt[3 * 32 + lrx];
        c1[0] = bt[0 * 32 + (lrx ^ 16)]; c1[1] = bt[1 * 32 + (lrx ^ 16)];
        c1[2] = bt[2 * 32 + (lrx ^ 16)]; c1[3] = bt[3 * 32 + (lrx ^ 16)];

        f32x4 s0 = __builtin_amdgcn_mfma_f32_16x16x32_bf16(qf, ck0, c0, 0, 0, 0);
        f32x4 s1 = __builtin_amdgcn_mfma_f32_16x16x32_bf16(qf, ck1, c1, 0, 0, 0);

        float pm0 = fmaxf(s0[0], s1[0]);
        float pm1 = fmaxf(s0[1], s1[1]);
        float pm2 = fmaxf(s0[2], s1[2]);
        float pm3 = fmaxf(s0[3], s1[3]);
        bool ev = (pm0 > m0v) || (pm1 > m1v) || (pm2 > m2v) || (pm3 > m3v);
        if (__any(ev)) {
            RMAX(pm0) RMAX(pm1) RMAX(pm2) RMAX(pm3)
            float t0 = fmaxf(m0v, pm0), t1 = fmaxf(m1v, pm1);
            float t2 = fmaxf(m2v, pm2), t3 = fmaxf(m3v, pm3);
            float sc0 = __expf(m0v - t0), sc1 = __expf(m1v - t1);
            float sc2 = __expf(m2v - t2), sc3 = __expf(m3v - t3);
            m0v = t0; m1v = t1; m2v = t2; m3v = t3;
            l0 *= sc0; l1 *= sc1; l2 *= sc2; l3 *= sc3;
            acc0[0] *= sc0; acc0[1] *= sc1; acc0[2] *= sc2; acc0[3] *= sc3;
            acc1[0] *= sc0; acc1[1] *= sc1; acc1[2] *= sc2; acc1[3] *= sc3;
        }
        float p00 = __expf(s0[0] - m0v), p01 = __expf(s0[1] - m1v);
        float p02 = __expf(s0[2] - m2v), p03 = __expf(s0[3] - m3v);
        float p10 = __expf(s1[0] - m0v), p11 = __expf(s1[1] - m1v);
        float p12 = __expf(s1[2] - m2v), p13 = __expf(s1[3] - m3v);
        l0 += p00 + p10; l1 += p01 + p11; l2 += p02 + p12; l3 += p03 + p13;

        u16* pw = &Plds[w][0][lq][lr];
        pw[0 * 64] = b16(p00); pw[1 * 64] = b16(p01);
        pw[2 * 64] = b16(p02); pw[3 * 64] = b16(p03);
        pw[4 * 64] = b16(p10); pw[5 * 64] = b16(p11);
        pw[6 * 64] = b16(p12); pw[7 * 64] = b16(p13);

        const bf16x8 pa = *(const bf16x8*)&Plds[w][(lq >> 1) * 4 + (lr & 3)][lr >> 2][(lq & 1) * 8];
        acc0 = __builtin_amdgcn_mfma_f32_16x16x32_bf16(pa, cv0, acc0, 0, 0, 0);
        acc1 = __builtin_amdgcn_mfma_f32_16x16x32_bf16(pa, cv1, acc1, 0, 0, 0);

        cur = (cur == 2) ? 0 : cur + 1;
        nxt = (nxt == 2) ? 0 : nxt + 1;
    }
#undef STAGE
#undef KVLOAD

    RSUM(l0) RSUM(l1) RSUM(l2) RSUM(l3)

    // ---- in-LDS merge of key-halves ----
    asm volatile("s_waitcnt vmcnt(0)" ::: "memory");   // drain stray bias DMA into Btl[w]
    float* P = (float*)&Btl[w][0][0][0];               // wave-private 6 KB region
    if (kh == 1) {                                     // waves 2,3: publish partials
#pragma unroll
        for (int r = 0; r < 4; r++) {
            const int row = lq * 4 + r;
            P[row * 32 + lr]      = acc0[r];
            P[row * 32 + 16 + lr] = acc1[r];
        }
        if (lr == 0) {
            P[512 + lq * 4 + 0] = m0v; P[512 + lq * 4 + 1] = m1v;
            P[512 + lq * 4 + 2] = m2v; P[512 + lq * 4 + 3] = m3v;
            P[528 + lq * 4 + 0] = l0;  P[528 + lq * 4 + 1] = l1;
            P[528 + lq * 4 + 2] = l2;  P[528 + lq * 4 + 3] = l3;
        }
    }
    __syncthreads();
    if (kh == 1) return;                               // no further barriers below

    const float* PB = (const float*)&Btl[w + 2][0][0][0];
    const float mA[4] = {m0v, m1v, m2v, m3v};
    const float lA[4] = {l0, l1, l2, l3};

    const u16* Gb = Gw + (size_t)(b * N_ + qb + rp * 16 + lq * 4) * CIN + h * CH + lr;
    u16* Ob = Owg + (size_t)(b * N_ + qb + rp * 16 + lq * 4) * CIN + h * CH + lr;
#pragma unroll
    for (int r = 0; r < 4; r++) {
        const int row = lq * 4 + r;
        const float mB = PB[512 + row];
        const float lB = PB[528 + row];
        const float ob0 = PB[row * 32 + lr];
        const float ob1 = PB[row * 32 + 16 + lr];
        const float mM = fmaxf(mA[r], mB);
        const float sA = __expf(mA[r] - mM), sB = __expf(mB - mM);
        const float rr = 1.0f / (lA[r] * sA + lB * sB);
        const float a0 = (r == 0 ? acc0[0] : r == 1 ? acc0[1] : r == 2 ? acc0[2] : acc0[3]);
        const float a1 = (r == 0 ? acc1[0] : r == 1 ? acc1[1] : r == 2 ? acc1[2] : acc1[3]);
        const float g0 = bf2f(Gb[r * CIN]), g1 = bf2f(Gb[r * CIN + 16]);
        Ob[r * CIN]      = b16((a0 * sA + ob0 * sB) * rr * g0);
        Ob[r * CIN + 16] = b16((a1 * sA + ob1 * sB) * rr * g1);
    }
}

// ---------------------------------------------------------------------------
// D3: out = Owg @ Wo + bo  (staged 64x64 core, round-3 validated)
// ---------------------------------------------------------------------------
__global__ __launch_bounds__(256, 4)
void out_mfma(const u16* __restrict__ Owg, const u16* __restrict__ WoT,
              const float* __restrict__ bo, float* __restrict__ out)
{
    const int tid = threadIdx.x, w = tid >> 6, l = tid & 63, lr = l & 15, lq = l >> 4;
    const int m0 = blockIdx.y * 64 + w * 16, n0 = blockIdx.x * 64;

    __shared__ u16 At[64][LDW];
    __shared__ u16 Bt[64][LDW];

    const u16* Arows = Owg + (size_t)(blockIdx.y * 64) * CIN;
    const u16* Brows = WoT + (size_t)(blockIdx.x * 64) * CIN;

    f32x4 acc[4] = {{0,0,0,0},{0,0,0,0},{0,0,0,0},{0,0,0,0}};

    stg_b16(Arows, At, tid);
    stg_b16(Brows, Bt, tid);
    __syncthreads();
    bf16x8 ra[4], rb[4];
    ld1_b16(Arows, ra, tid);
    ld1_b16(Brows, rb, tid);
    compute_phase(At, Bt, w, lr, lq, acc);
    __syncthreads();
    wr1_b16(ra, At, tid);
    wr1_b16(rb, Bt, tid);
    __syncthreads();
    compute_phase(At, Bt, w, lr, lq, acc);

#pragma unroll
    for (int nt = 0; nt < 4; nt++) {
        const float bb = bo[n0 + nt * 16 + lr];
#pragma unroll
        for (int r = 0; r < 4; r++)
            out[(size_t)(m0 + lq * 4 + r) * CIN + n0 + nt * 16 + lr] = acc[nt][r] + bb;
    }
}

// ---------------------------------------------------------------------------
extern "C" void kernel_launch(void* const* d_in, const int* in_sizes, int n_in,
                              void* d_out, int out_size, void* d_ws, size_t ws_size,
                              hipStream_t stream)
{
    const float* qx   = (const float*)d_in[0];
    const float* kvx  = (const float*)d_in[1];
    const float* bias = (const float*)d_in[2];
    const float* Wq = (const float*)d_in[3];
    const float* Wk = (const float*)d_in[4];
    const float* Wv = (const float*)d_in[5];
    const float* Wg = (const float*)d_in[6];
    const float* bg = (const float*)d_in[7];
    const float* Wo = (const float*)d_in[8];
    const float* bo = (const float*)d_in[9];
    float* out = (float*)d_out;

    char* ws = (char*)d_ws;
    const size_t SZB = (size_t)B_ * N_ * CIN * 2;   // 2 MB per bf16 [4096][256]
    u16* Qw   = (u16*)(ws + 2 * SZB);
    u16* Kw   = (u16*)(ws + 3 * SZB);
    u16* Vt   = (u16*)(ws + 4 * SZB);
    u16* Gw   = (u16*)(ws + 5 * SZB);
    u16* Owg  = (u16*)(ws + 6 * SZB);
    const size_t WSZ = (size_t)CIN * CIN * 2;       // 128 KB per bf16 weight
    u16* WoT  = (u16*)(ws + 7 * SZB + 4 * WSZ);

    proj_kernel<<<dim3(1040), 256, 0, stream>>>(qx, kvx, Wq, Wk, Wv, Wg, bg, Wo,
                                                Qw, Kw, Vt, Gw, WoT);
    attn_kernel<<<dim3(1024), 256, 0, stream>>>(Qw, Kw, Vt, bias, Gw, Owg);
    out_mfma<<<dim3(4, 64, 1), 256, 0, stream>>>(Owg, WoT, bo, out);
}